// Round 7
// baseline (75093.463 us; speedup 1.0000x reference)
//
#include <hip/hip_runtime.h>
#include <hip/hip_bf16.h>
#include <math.h>

#define T_DEC 256

__device__ __forceinline__ float sigf(float x) { return 1.0f / (1.0f + expf(-x)); }

// ---------------- mlen normalizer (robust to int32/int64/float storage) ----
__global__ void convert_mlen(const void* p, int* out) {
    int b = threadIdx.x;            // 32 threads
    const int* pi = (const int*)p;
    const float* pf = (const float*)p;
    __shared__ int mode;
    if (b == 0) {
        int i0 = pi[0], i1 = pi[1];
        float f0 = pf[0];
        if (i0 >= 1 && i0 <= 512 && i1 == 0) mode = 2;          // int64
        else if (i0 >= 1 && i0 <= 512) mode = 0;                // int32
        else if (f0 >= 1.0f && f0 <= 512.0f) mode = 1;          // float32
        else mode = 0;
    }
    __syncthreads();
    int v;
    if (mode == 2)      v = pi[2 * b];
    else if (mode == 1) v = (int)(pf[b] + 0.5f);
    else                v = pi[b];
    if (v < 1) v = 1;
    if (v > 256) v = 256;
    out[b] = v;
}

// ---------------- prologue kernels ----------------

// pm[r][d] = mem[r] . W_mem[d] ; r = b*256+t
__global__ __launch_bounds__(128) void proc_mem(const float* __restrict__ mem,
                                                const float* __restrict__ Wm,
                                                float* __restrict__ pm) {
    int r = blockIdx.x;
    int d = threadIdx.x;           // 0..127
    __shared__ float xs[512];
    for (int k = d; k < 512; k += 128) xs[k] = mem[(size_t)r * 512 + k];
    __syncthreads();
    const float* wr = Wm + (size_t)d * 512;
    float s = 0.f;
    for (int k = 0; k < 512; k += 4) {
        float4 w = *reinterpret_cast<const float4*>(wr + k);
        s = fmaf(xs[k], w.x, s); s = fmaf(xs[k+1], w.y, s);
        s = fmaf(xs[k+2], w.z, s); s = fmaf(xs[k+3], w.w, s);
    }
    pm[(size_t)r * 128 + d] = s;
}

__global__ void zero_f(float* __restrict__ p, int n) {
    int i = blockIdx.x * blockDim.x + threadIdx.x;
    if (i < n) p[i] = 0.0f;
}

// ---------------- per-step kernels ----------------

// pre_t[b][o] = relu(relu(dec_in_t[b] @ W1.T) @ W2.T)[o], dec_in_t = inputs[:,t-1] (0 if t==0)
__global__ __launch_bounds__(256) void prenet_step(const float* __restrict__ inputs,
                                                   const float* __restrict__ W1,
                                                   const float* __restrict__ W2,
                                                   float* __restrict__ pre_t,
                                                   int t) {
    int b = blockIdx.x;            // 0..31
    int o = threadIdx.x;           // 0..255
    __shared__ float xs[80];
    __shared__ float h1[256];
    if (o < 80) xs[o] = (t == 0) ? 0.0f : inputs[((size_t)b * T_DEC + (t - 1)) * 80 + o];
    __syncthreads();
    {
        const float* wr = W1 + (size_t)o * 80;
        float s = 0.f;
        #pragma unroll 8
        for (int k = 0; k < 80; ++k) s = fmaf(xs[k], wr[k], s);
        h1[o] = fmaxf(s, 0.0f);
    }
    __syncthreads();
    {
        const float* wr = W2 + (size_t)o * 256;
        float s = 0.f;
        for (int k = 0; k < 256; k += 4) {
            float4 w = *reinterpret_cast<const float4*>(wr + k);
            s = fmaf(h1[k], w.x, s); s = fmaf(h1[k+1], w.y, s);
            s = fmaf(h1[k+2], w.z, s); s = fmaf(h1[k+3], w.w, s);
        }
        pre_t[(size_t)b * 256 + o] = fmaxf(s, 0.0f);
    }
}

// z(32,4096) = [x0|x1|xh](32,K) @ [Wih|Whh]^T + bias
#define TJ 16
__global__ __launch_bounds__(256) void gemm_z(const float* __restrict__ Wih,
                                              const float* __restrict__ Whh,
                                              const float* __restrict__ bias,
                                              const float* __restrict__ x0, int len0,
                                              const float* __restrict__ x1, int len1,
                                              const float* __restrict__ xh,
                                              float* __restrict__ z) {
    const int Kih = len0 + len1;
    const int Ktot = Kih + 1024;
    const int jb = blockIdx.x * TJ;
    const int tid = threadIdx.x;
    const int b = tid & 31;
    const int jl = tid >> 5;               // 0..7
    __shared__ float Xs[32][65];
    __shared__ float Ws[TJ][65];
    float acc0 = 0.f, acc1 = 0.f;
    for (int k0 = 0; k0 < Ktot; k0 += 64) {
        {
            int i = tid;
            #pragma unroll
            for (int it = 0; it < 2; ++it, i += 256) {
                int bb = i >> 4;
                int k4 = (i & 15) << 2;
                int k = k0 + k4;
                const float* src; int kk;
                if (k < len0)     { src = x0 + (size_t)bb * len0; kk = k; }
                else if (k < Kih) { src = x1 + (size_t)bb * len1; kk = k - len0; }
                else              { src = xh + (size_t)bb * 1024; kk = k - Kih; }
                float4 v = *reinterpret_cast<const float4*>(src + kk);
                Xs[bb][k4 + 0] = v.x; Xs[bb][k4 + 1] = v.y;
                Xs[bb][k4 + 2] = v.z; Xs[bb][k4 + 3] = v.w;
            }
        }
        {
            int jr = tid >> 4;
            int k4 = (tid & 15) << 2;
            const float* wr; int kk;
            if (k0 < Kih) { wr = Wih + (size_t)(jb + jr) * Kih;  kk = k0 + k4; }
            else          { wr = Whh + (size_t)(jb + jr) * 1024; kk = k0 - Kih + k4; }
            float4 v = *reinterpret_cast<const float4*>(wr + kk);
            Ws[jr][k4 + 0] = v.x; Ws[jr][k4 + 1] = v.y;
            Ws[jr][k4 + 2] = v.z; Ws[jr][k4 + 3] = v.w;
        }
        __syncthreads();
        #pragma unroll
        for (int kk = 0; kk < 64; ++kk) {
            float xv = Xs[b][kk];
            acc0 = fmaf(xv, Ws[jl][kk], acc0);
            acc1 = fmaf(xv, Ws[jl + 8][kk], acc1);
        }
        __syncthreads();
    }
    int j0 = jb + jl, j1 = jb + jl + 8;
    z[(size_t)b * 4096 + j0] = acc0 + bias[j0];
    z[(size_t)b * 4096 + j1] = acc1 + bias[j1];
}

// h,c update from z (i,f,g,o gate order)
__global__ __launch_bounds__(256) void lstm_gates(const float* __restrict__ z,
                                                  float* __restrict__ h,
                                                  float* __restrict__ c) {
    int idx = blockIdx.x * blockDim.x + threadIdx.x;   // 0..32767
    int b = idx >> 10, j = idx & 1023;
    const float* zb = z + (size_t)b * 4096;
    float zi = zb[j], zf = zb[j + 1024], zg = zb[j + 2048], zo = zb[j + 3072];
    float cn = sigf(zf) * c[idx] + sigf(zi) * tanhf(zg);
    float hn = sigf(zo) * tanhf(cn);
    c[idx] = cn;
    h[idx] = hn;
}

// pq[b][d] = h_a[b] . W_q[d]
__global__ __launch_bounds__(128) void pq_kernel(const float* __restrict__ h_a,
                                                 const float* __restrict__ Wq,
                                                 float* __restrict__ pq) {
    int b = blockIdx.x, d = threadIdx.x;
    __shared__ float hs[1024];
    for (int k = d; k < 1024; k += 128) hs[k] = h_a[(size_t)b * 1024 + k];
    __syncthreads();
    const float* wr = Wq + (size_t)d * 1024;
    float s = 0.f;
    for (int k = 0; k < 1024; k += 4) {
        float4 w = *reinterpret_cast<const float4*>(wr + k);
        s = fmaf(hs[k], w.x, s); s = fmaf(hs[k+1], w.y, s);
        s = fmaf(hs[k+2], w.z, s); s = fmaf(hs[k+3], w.w, s);
    }
    pq[(size_t)b * 128 + d] = s;
}

// energies[b][t] for a 32-t chunk: conv + loc-dense + tanh + v dot + mask
__global__ __launch_bounds__(256) void attn_energies(const float* __restrict__ pq,
                                                     const float* __restrict__ att_w,
                                                     const float* __restrict__ cum,
                                                     const float* __restrict__ Wlc,
                                                     const float* __restrict__ Wld,
                                                     const float* __restrict__ vatt,
                                                     const float* __restrict__ pm,
                                                     const int* __restrict__ mlen,
                                                     float* __restrict__ ebuf) {
    int b = blockIdx.y;
    int tg = blockIdx.x << 5;       // 32 t per block
    int tid = threadIdx.x;
    __shared__ float aw0[64], aw1[64];
    __shared__ float convs[32][33];
    __shared__ float pqs[128], vs[128];
    if (tid < 128) {
        int c = tid >> 6, i = tid & 63;
        int pos = tg - 15 + i;
        float v = 0.f;
        if (i < 62 && pos >= 0 && pos < 256) v = (c == 0 ? att_w : cum)[(size_t)b * 256 + pos];
        (c == 0 ? aw0 : aw1)[i] = v;
    } else {
        int i = tid - 128;
        pqs[i] = pq[(size_t)b * 128 + i];
        vs[i] = vatt[i];
    }
    __syncthreads();
    for (int i = tid; i < 1024; i += 256) {
        int tl = i >> 5, f = i & 31;
        const float* w0 = Wlc + (size_t)f * 62;   // (f,0,0..30) then (f,1,0..30)
        float s = 0.f;
        #pragma unroll
        for (int k = 0; k < 31; ++k) {
            s = fmaf(aw0[tl + k], w0[k], s);
            s = fmaf(aw1[tl + k], w0[31 + k], s);
        }
        convs[tl][f] = s;
    }
    __syncthreads();
    int tl = tid >> 3, dg = tid & 7;
    int t = tg + tl;
    const float* pmrow = pm + ((size_t)b * 256 + t) * 128;
    float e = 0.f;
    for (int dd = 0; dd < 16; ++dd) {
        int d = dg * 16 + dd;
        const float* wld = Wld + (size_t)d * 32;
        float loc = 0.f;
        #pragma unroll
        for (int f = 0; f < 32; ++f) loc = fmaf(convs[tl][f], wld[f], loc);
        float a = tanhf(pqs[d] + loc + pmrow[d]);
        e = fmaf(a, vs[d], e);
    }
    e += __shfl_xor(e, 1); e += __shfl_xor(e, 2); e += __shfl_xor(e, 4);
    if (dg == 0) {
        if (t >= mlen[b]) e = -1e9f;
        ebuf[(size_t)b * 256 + t] = e;
    }
}

// softmax over t, ctx = w @ memory, cum += w, write alignment (fp32)
__global__ __launch_bounds__(256) void softmax_ctx(const float* __restrict__ ebuf,
                                                   const float* __restrict__ mem,
                                                   float* __restrict__ att_w,
                                                   float* __restrict__ cum,
                                                   float* __restrict__ ctx,
                                                   float* __restrict__ align_out,
                                                   int t) {
    int b = blockIdx.x, tid = threadIdx.x;
    __shared__ float ws[256];
    __shared__ float red[4];
    float e = ebuf[(size_t)b * 256 + tid];
    float m = e;
    #pragma unroll
    for (int o = 32; o >= 1; o >>= 1) m = fmaxf(m, __shfl_xor(m, o));
    if ((tid & 63) == 0) red[tid >> 6] = m;
    __syncthreads();
    m = fmaxf(fmaxf(red[0], red[1]), fmaxf(red[2], red[3]));
    __syncthreads();
    float p = expf(e - m);
    float s = p;
    #pragma unroll
    for (int o = 32; o >= 1; o >>= 1) s += __shfl_xor(s, o);
    if ((tid & 63) == 0) red[tid >> 6] = s;
    __syncthreads();
    s = red[0] + red[1] + red[2] + red[3];
    float w = p / s;
    ws[tid] = w;
    att_w[(size_t)b * 256 + tid] = w;
    cum[(size_t)b * 256 + tid] += w;
    align_out[((size_t)b * T_DEC + t) * 256 + tid] = w;
    __syncthreads();
    for (int d = tid; d < 512; d += 256) {
        const float* mb = mem + (size_t)b * 256 * 512 + d;
        float s2 = 0.f;
        for (int tt = 0; tt < 256; ++tt) s2 = fmaf(ws[tt], mb[(size_t)tt * 512], s2);
        ctx[(size_t)b * 512 + d] = s2;
    }
}

// mel (80) + gate (1) projection from hc=[h_d|ctx], fp32 out
__global__ __launch_bounds__(128) void proj_out(const float* __restrict__ h_d,
                                                const float* __restrict__ ctx,
                                                const float* __restrict__ Wp,
                                                const float* __restrict__ bp,
                                                const float* __restrict__ Wg,
                                                const float* __restrict__ bg,
                                                float* __restrict__ mel_out,
                                                float* __restrict__ gate_out,
                                                int t) {
    int b = blockIdx.x, tid = threadIdx.x;
    __shared__ float hc[1536];
    for (int k = tid; k < 1024; k += 128) hc[k] = h_d[(size_t)b * 1024 + k];
    for (int k = tid; k < 512; k += 128) hc[1024 + k] = ctx[(size_t)b * 512 + k];
    __syncthreads();
    if (tid < 81) {
        const float* wr = (tid < 80) ? (Wp + (size_t)tid * 1536) : Wg;
        float s = (tid < 80) ? bp[tid] : bg[0];
        for (int k = 0; k < 1536; k += 4) {
            float4 w = *reinterpret_cast<const float4*>(wr + k);
            s = fmaf(hc[k], w.x, s); s = fmaf(hc[k+1], w.y, s);
            s = fmaf(hc[k+2], w.z, s); s = fmaf(hc[k+3], w.w, s);
        }
        if (tid < 80) mel_out[((size_t)b * T_DEC + t) * 80 + tid] = s;
        else          gate_out[(size_t)b * T_DEC + t] = s;
    }
}

// ---------------- host ----------------

extern "C" void kernel_launch(void* const* d_in, const int* in_sizes, int n_in,
                              void* d_out, int out_size, void* d_ws, size_t ws_size,
                              hipStream_t stream) {
    const float* enc    = (const float*)d_in[0];
    const float* inputs = (const float*)d_in[1];
    const void*  mlen_raw = d_in[2];
    const float* W_pre1 = (const float*)d_in[3];
    const float* W_pre2 = (const float*)d_in[4];
    const float* Wih_a  = (const float*)d_in[5];
    const float* Whh_a  = (const float*)d_in[6];
    const float* b_a    = (const float*)d_in[7];
    const float* W_q    = (const float*)d_in[8];
    const float* W_mem  = (const float*)d_in[9];
    const float* Wlc    = (const float*)d_in[10];
    const float* Wld    = (const float*)d_in[11];
    const float* v_att  = (const float*)d_in[12];
    const float* Wih_d  = (const float*)d_in[13];
    const float* Whh_d  = (const float*)d_in[14];
    const float* b_d    = (const float*)d_in[15];
    const float* W_proj = (const float*)d_in[16];
    const float* b_proj = (const float*)d_in[17];
    const float* W_gate = (const float*)d_in[18];
    const float* b_gate = (const float*)d_in[19];

    float* ws = (float*)d_ws;
    // workspace layout (floats) — total ~5.46 MB
    const size_t off_pm   = 0;                      // 32*256*128 = 1048576
    const size_t off_pret = off_pm + 1048576;       // 32*256
    const size_t off_ha   = off_pret + 8192;        // 32*1024
    const size_t off_ca   = off_ha + 32768;
    const size_t off_hd   = off_ca + 32768;
    const size_t off_cd   = off_hd + 32768;
    const size_t off_aw   = off_cd + 32768;         // 32*256
    const size_t off_cum  = off_aw + 8192;          // 32*256
    const size_t off_ctx  = off_cum + 8192;         // 32*512
    const size_t off_z    = off_ctx + 16384;        // 32*4096
    const size_t off_e    = off_z + 131072;         // 32*256
    const size_t off_pq   = off_e + 8192;           // 32*128
    const size_t off_ml   = off_pq + 4096;          // 32 ints

    float* pm    = ws + off_pm;
    float* pre_t = ws + off_pret;
    float* h_a   = ws + off_ha;
    float* c_a   = ws + off_ca;
    float* h_d   = ws + off_hd;
    float* c_d   = ws + off_cd;
    float* aw    = ws + off_aw;
    float* cum   = ws + off_cum;
    float* ctx   = ws + off_ctx;
    float* zb    = ws + off_z;
    float* ebuf  = ws + off_e;
    float* pqb   = ws + off_pq;
    int*   mlen  = (int*)(ws + off_ml);

    // OUTPUTS ARE FLOAT32 (reference output dtype). mel | gate | align concat.
    float* out       = (float*)d_out;
    float* mel_out   = out;                               // 32*256*80
    float* gate_out  = out + (size_t)32 * 256 * 80;       // 32*256
    float* align_out = gate_out + (size_t)32 * 256;       // 32*256*256

    // prologue
    convert_mlen<<<1, 32, 0, stream>>>(mlen_raw, mlen);
    proc_mem<<<8192, 128, 0, stream>>>(enc, W_mem, pm);
    {
        int nstate = 4 * 32 * 1024 + 2 * 32 * 256 + 32 * 512;
        zero_f<<<(nstate + 255) / 256, 256, 0, stream>>>(h_a, nstate);
    }

    for (int t = 0; t < T_DEC; ++t) {
        prenet_step<<<32, 256, 0, stream>>>(inputs, W_pre1, W_pre2, pre_t, t);
        gemm_z<<<256, 256, 0, stream>>>(Wih_a, Whh_a, b_a,
                                        pre_t, 256, ctx, 512, h_a, zb);
        lstm_gates<<<128, 256, 0, stream>>>(zb, h_a, c_a);
        pq_kernel<<<32, 128, 0, stream>>>(h_a, W_q, pqb);
        attn_energies<<<dim3(8, 32), 256, 0, stream>>>(pqb, aw, cum, Wlc, Wld, v_att,
                                                       pm, mlen, ebuf);
        softmax_ctx<<<32, 256, 0, stream>>>(ebuf, enc, aw, cum, ctx, align_out, t);
        gemm_z<<<256, 256, 0, stream>>>(Wih_d, Whh_d, b_d,
                                        h_a, 1024, ctx, 512, h_d, zb);
        lstm_gates<<<128, 256, 0, stream>>>(zb, h_d, c_d);
        proj_out<<<32, 128, 0, stream>>>(h_d, ctx, W_proj, b_proj, W_gate, b_gate,
                                         mel_out, gate_out, t);
    }
}

// Round 8
// 66235.980 us; speedup vs baseline: 1.1337x; 1.1337x over previous
//
#include <hip/hip_runtime.h>
#include <math.h>

#define T_DEC 256

__device__ __forceinline__ float sigf(float x) { return 1.0f / (1.0f + expf(-x)); }

// ---------------- mlen normalizer (robust to int32/int64/float storage) ----
__global__ void convert_mlen(const void* p, int* out) {
    int b = threadIdx.x;            // 32 threads
    const int* pi = (const int*)p;
    const float* pf = (const float*)p;
    __shared__ int mode;
    if (b == 0) {
        int i0 = pi[0], i1 = pi[1];
        float f0 = pf[0];
        if (i0 >= 1 && i0 <= 512 && i1 == 0) mode = 2;          // int64
        else if (i0 >= 1 && i0 <= 512) mode = 0;                // int32
        else if (f0 >= 1.0f && f0 <= 512.0f) mode = 1;          // float32
        else mode = 0;
    }
    __syncthreads();
    int v;
    if (mode == 2)      v = pi[2 * b];
    else if (mode == 1) v = (int)(pf[b] + 0.5f);
    else                v = pi[b];
    if (v < 1) v = 1;
    if (v > 256) v = 256;
    out[b] = v;
}

__global__ void zero_f(float* __restrict__ p, int n) {
    int i = blockIdx.x * blockDim.x + threadIdx.x;
    if (i < n) p[i] = 0.0f;
}

// ---------------- prologue ----------------

// prenet for ALL steps (input-only): r = t*32+b, both layers in one block
__global__ __launch_bounds__(256) void prenet_all(const float* __restrict__ inputs,
                                                  const float* __restrict__ W1,
                                                  const float* __restrict__ W2,
                                                  float* __restrict__ pre) {
    int r = blockIdx.x;            // 0..8191
    int t = r >> 5, b = r & 31;
    int o = threadIdx.x;           // 0..255
    __shared__ float xs[80];
    __shared__ float h1[256];
    if (o < 80) xs[o] = (t == 0) ? 0.0f : inputs[((size_t)b * T_DEC + (t - 1)) * 80 + o];
    __syncthreads();
    {
        const float* wr = W1 + (size_t)o * 80;
        float s = 0.f;
        #pragma unroll 8
        for (int k = 0; k < 80; ++k) s = fmaf(xs[k], wr[k], s);
        h1[o] = fmaxf(s, 0.0f);
    }
    __syncthreads();
    {
        const float* wr = W2 + (size_t)o * 256;
        float s = 0.f;
        for (int k = 0; k < 256; k += 4) {
            float4 w = *reinterpret_cast<const float4*>(wr + k);
            s = fmaf(h1[k], w.x, s); s = fmaf(h1[k+1], w.y, s);
            s = fmaf(h1[k+2], w.z, s); s = fmaf(h1[k+3], w.w, s);
        }
        pre[(size_t)r * 256 + o] = fmaxf(s, 0.0f);
    }
}

// pm[r][d] = mem[r] . W_mem[d] ; r = b*256+t
__global__ __launch_bounds__(128) void proc_mem(const float* __restrict__ mem,
                                                const float* __restrict__ Wm,
                                                float* __restrict__ pm) {
    int r = blockIdx.x;
    int d = threadIdx.x;
    __shared__ float xs[512];
    for (int k = d; k < 512; k += 128) xs[k] = mem[(size_t)r * 512 + k];
    __syncthreads();
    const float* wr = Wm + (size_t)d * 512;
    float s = 0.f;
    for (int k = 0; k < 512; k += 4) {
        float4 w = *reinterpret_cast<const float4*>(wr + k);
        s = fmaf(xs[k], w.x, s); s = fmaf(xs[k+1], w.y, s);
        s = fmaf(xs[k+2], w.z, s); s = fmaf(xs[k+3], w.w, s);
    }
    pm[(size_t)r * 128 + d] = s;
}

// wqT[k*128+d] = Wq[d*1024+k]
__global__ __launch_bounds__(256) void transpose_wq(const float* __restrict__ Wq,
                                                    float* __restrict__ wqT) {
    int i = blockIdx.x * 256 + threadIdx.x;   // 0..131071
    int d = i & 127, k = i >> 7;
    wqT[i] = Wq[(size_t)d * 1024 + k];
}

// ---------------- K_AD: gemm_a(t+1) + gemm_d(t), gates fused ----------------
// Block = 4 hidden units x 4 gates = 16 W rows, all 32 b. 256 threads.
// blocks 0..255 = a-part, 256..511 = d-part.
__global__ __launch_bounds__(256) void kad(
    const float* __restrict__ WihA, const float* __restrict__ WhhA, const float* __restrict__ bA,
    const float* __restrict__ WihD, const float* __restrict__ WhhD, const float* __restrict__ bD,
    const float* __restrict__ preT,   // pre(t+1) base (32 rows stride 256)
    const float* __restrict__ ctx,    // ctx(t) (32 rows stride 512)
    const float* __restrict__ hAin, float* __restrict__ hAout, float* __restrict__ cA,
    const float* __restrict__ hDin, float* __restrict__ hDout, float* __restrict__ cD,
    int do_a, int do_d)
{
    int blk = blockIdx.x;
    bool isA = blk < 256;
    if (isA ? !do_a : !do_d) return;
    const float *Wih, *Whh, *bias, *x0, *x1, *xh;
    float *hout, *cio;
    int len0, Kih, Ktot, pb;
    if (isA) { Wih=WihA; Whh=WhhA; bias=bA; x0=preT; len0=256;  x1=ctx; xh=hAin;
               hout=hAout; cio=cA; Kih=768;  Ktot=1792; pb=blk; }
    else     { Wih=WihD; Whh=WhhD; bias=bD; x0=hAin; len0=1024; x1=ctx; xh=hDin;
               hout=hDout; cio=cD; Kih=1536; Ktot=2560; pb=blk-256; }
    const int hb = pb * 4;                 // hidden base (4 per block)
    const int tid = threadIdx.x;
    const int b = tid & 31;
    const int jl = tid >> 5;               // 0..7 -> local rows jl, jl+8
    __shared__ float Xs[32][68];
    __shared__ float Ws[16][68];
    __shared__ float zs[32][17];
    float acc0 = 0.f, acc1 = 0.f;
    for (int k0 = 0; k0 < Ktot; k0 += 64) {
        // stage X: 32 b x 64 k (512 float4, 2/thread)
        {
            int i = tid;
            #pragma unroll
            for (int it = 0; it < 2; ++it, i += 256) {
                int bb = i >> 4;
                int k4 = (i & 15) << 2;
                int k = k0 + k4;
                const float* src; int kk;
                if (k < len0)     { src = x0 + (size_t)bb * len0; kk = k; }
                else if (k < Kih) { src = x1 + (size_t)bb * 512;  kk = k - len0; }
                else              { src = xh + (size_t)bb * 1024; kk = k - Kih; }
                *reinterpret_cast<float4*>(&Xs[bb][k4]) =
                    *reinterpret_cast<const float4*>(src + kk);
            }
        }
        // stage W: 16 rows x 64 k (256 float4, 1/thread)
        {
            int r = tid >> 4;
            int k4 = (tid & 15) << 2;
            int grow = (r >> 2) * 1024 + hb + (r & 3);   // gate-major global row
            const float* wr; int kk;
            if (k0 < Kih) { wr = Wih + (size_t)grow * Kih;  kk = k0 + k4; }
            else          { wr = Whh + (size_t)grow * 1024; kk = k0 - Kih + k4; }
            *reinterpret_cast<float4*>(&Ws[r][k4]) =
                *reinterpret_cast<const float4*>(wr + kk);
        }
        __syncthreads();
        #pragma unroll
        for (int q = 0; q < 16; ++q) {
            float4 xv = *reinterpret_cast<const float4*>(&Xs[b][q << 2]);
            float4 wa = *reinterpret_cast<const float4*>(&Ws[jl][q << 2]);
            float4 wb = *reinterpret_cast<const float4*>(&Ws[jl + 8][q << 2]);
            acc0 = fmaf(xv.x, wa.x, acc0); acc0 = fmaf(xv.y, wa.y, acc0);
            acc0 = fmaf(xv.z, wa.z, acc0); acc0 = fmaf(xv.w, wa.w, acc0);
            acc1 = fmaf(xv.x, wb.x, acc1); acc1 = fmaf(xv.y, wb.y, acc1);
            acc1 = fmaf(xv.z, wb.z, acc1); acc1 = fmaf(xv.w, wb.w, acc1);
        }
        __syncthreads();
    }
    // gate exchange + LSTM update
    {
        int g0 = jl >> 2, u = jl & 3;
        int grow0 = g0 * 1024 + hb + u;
        zs[b][jl]     = acc0 + bias[grow0];
        zs[b][jl + 8] = acc1 + bias[grow0 + 2048];
    }
    __syncthreads();
    if (tid < 128) {
        int bb = tid & 31, uu = tid >> 5;          // uu 0..3
        float zi = zs[bb][uu],     zf = zs[bb][4 + uu];
        float zg = zs[bb][8 + uu], zo = zs[bb][12 + uu];
        int idx = bb * 1024 + hb + uu;
        float cn = sigf(zf) * cio[idx] + sigf(zi) * tanhf(zg);
        float hn = sigf(zo) * tanhf(cn);
        cio[idx] = cn;
        hout[idx] = hn;
    }
}

// ---------------- K_PA: proj(t) [blocks 0..31] + attn(t+1) [blocks 32..63] ----
__global__ __launch_bounds__(256) void kpa(
    const float* __restrict__ enc, const float* __restrict__ pm,
    const float* __restrict__ wqT,
    const float* __restrict__ Wlc, const float* __restrict__ Wld,
    const float* __restrict__ vatt,
    const float* __restrict__ Wp, const float* __restrict__ bp,
    const float* __restrict__ Wg, const float* __restrict__ bg,
    const float* __restrict__ hA,      // h_a(t+1)
    const float* __restrict__ hD,      // h_d(t)
    const float* __restrict__ ctx_in,  // ctx(t) for proj
    float* __restrict__ ctx_out,       // ctx(t+1) written by attn
    float* __restrict__ aw, float* __restrict__ cum,
    const int* __restrict__ mlen,
    float* __restrict__ mel, float* __restrict__ gate,
    float* __restrict__ align_out,
    int t, int do_proj, int do_attn)
{
    const int tid = threadIdx.x;
    if (blockIdx.x < 32) {
        // ---- proj(t) ----
        if (!do_proj) return;
        int b = blockIdx.x;
        __shared__ float hc[1536];
        __shared__ float redp[164];
        for (int k = tid; k < 1024; k += 256) hc[k] = hD[(size_t)b * 1024 + k];
        for (int k = tid; k < 512; k += 256)  hc[1024 + k] = ctx_in[(size_t)b * 512 + k];
        __syncthreads();
        if (tid < 162) {
            int o = tid >> 1, hf = tid & 1;
            const float* wr = (o < 80) ? (Wp + (size_t)o * 1536) : Wg;
            float s = 0.f;
            int k0 = hf * 768;
            for (int k = k0; k < k0 + 768; k += 4) {
                float4 w = *reinterpret_cast<const float4*>(wr + k);
                s = fmaf(hc[k], w.x, s);   s = fmaf(hc[k+1], w.y, s);
                s = fmaf(hc[k+2], w.z, s); s = fmaf(hc[k+3], w.w, s);
            }
            redp[tid] = s;
        }
        __syncthreads();
        if (tid < 81) {
            float s = redp[2 * tid] + redp[2 * tid + 1];
            if (tid < 80) mel[((size_t)b * T_DEC + t) * 80 + tid] = s + bp[tid];
            else          gate[(size_t)b * T_DEC + t] = s + bg[0];
        }
        return;
    }
    // ---- attn(t+1) ----
    if (!do_attn) return;
    int b = blockIdx.x - 32;
    int tt = t + 1;
    __shared__ float hs[1024];
    __shared__ float red[256];
    __shared__ float pqs[128];
    __shared__ float vs[128];
    __shared__ float aw0s[288], aw1s[288];
    __shared__ float wlc0[31][32], wlc1[31][32];
    __shared__ float wlds[128][36];
    __shared__ float sm[256];
    __shared__ float red4[4];
    for (int k = tid; k < 1024; k += 256) hs[k] = hA[(size_t)b * 1024 + k];
    for (int i = tid; i < 288; i += 256) {
        int pos = i - 16;
        float v0 = 0.f, v1 = 0.f;
        if (pos >= 0 && pos < 256) {
            v0 = aw[(size_t)b * 256 + pos];
            v1 = cum[(size_t)b * 256 + pos];
        }
        aw0s[i] = v0; aw1s[i] = v1;
    }
    for (int i = tid; i < 992; i += 256) {
        int k = i >> 5, f = i & 31;
        wlc0[k][f] = Wlc[(size_t)f * 62 + k];
        wlc1[k][f] = Wlc[(size_t)f * 62 + 31 + k];
    }
    for (int i = tid; i < 4096; i += 256) wlds[i >> 5][i & 31] = Wld[i];
    if (tid < 128) vs[tid] = vatt[tid];
    __syncthreads();
    // pq (2-way split over k)
    {
        int d = tid & 127, hf = tid >> 7;
        float s = 0.f;
        int k0 = hf * 512;
        for (int k = k0; k < k0 + 512; ++k)
            s = fmaf(hs[k], wqT[(size_t)k * 128 + d], s);
        red[tid] = s;
    }
    __syncthreads();
    if (tid < 128) pqs[tid] = red[tid] + red[tid + 128];
    __syncthreads();
    // conv for this thread's enc position (held in registers)
    float cf[32];
    #pragma unroll
    for (int f = 0; f < 32; ++f) cf[f] = 0.f;
    for (int k = 0; k < 31; ++k) {
        float a0 = aw0s[tid + 1 + k], a1 = aw1s[tid + 1 + k];
        #pragma unroll
        for (int fq = 0; fq < 8; ++fq) {
            float4 w0 = *reinterpret_cast<const float4*>(&wlc0[k][fq << 2]);
            float4 w1 = *reinterpret_cast<const float4*>(&wlc1[k][fq << 2]);
            cf[fq*4+0] = fmaf(a0, w0.x, fmaf(a1, w1.x, cf[fq*4+0]));
            cf[fq*4+1] = fmaf(a0, w0.y, fmaf(a1, w1.y, cf[fq*4+1]));
            cf[fq*4+2] = fmaf(a0, w0.z, fmaf(a1, w1.z, cf[fq*4+2]));
            cf[fq*4+3] = fmaf(a0, w0.w, fmaf(a1, w1.w, cf[fq*4+3]));
        }
    }
    // energies
    float e = 0.f;
    {
        const float* pmr = pm + ((size_t)b * 256 + tid) * 128;
        for (int d = 0; d < 128; ++d) {
            float loc = 0.f;
            #pragma unroll
            for (int fq = 0; fq < 8; ++fq) {
                float4 w = *reinterpret_cast<const float4*>(&wlds[d][fq << 2]);
                loc = fmaf(cf[fq*4+0], w.x, loc); loc = fmaf(cf[fq*4+1], w.y, loc);
                loc = fmaf(cf[fq*4+2], w.z, loc); loc = fmaf(cf[fq*4+3], w.w, loc);
            }
            float a = tanhf(pqs[d] + loc + pmr[d]);
            e = fmaf(a, vs[d], e);
        }
    }
    if (tid >= mlen[b]) e = -1e9f;
    // softmax over 256
    float m = e;
    #pragma unroll
    for (int o = 32; o >= 1; o >>= 1) m = fmaxf(m, __shfl_xor(m, o));
    if ((tid & 63) == 0) red4[tid >> 6] = m;
    __syncthreads();
    m = fmaxf(fmaxf(red4[0], red4[1]), fmaxf(red4[2], red4[3]));
    __syncthreads();
    float p = expf(e - m);
    float s = p;
    #pragma unroll
    for (int o = 32; o >= 1; o >>= 1) s += __shfl_xor(s, o);
    if ((tid & 63) == 0) red4[tid >> 6] = s;
    __syncthreads();
    s = red4[0] + red4[1] + red4[2] + red4[3];
    float w = p / s;
    sm[tid] = w;
    aw[(size_t)b * 256 + tid] = w;
    cum[(size_t)b * 256 + tid] += w;
    align_out[((size_t)b * T_DEC + tt) * 256 + tid] = w;
    __syncthreads();
    // ctx(t+1)
    for (int d = tid; d < 512; d += 256) {
        const float* mb = enc + (size_t)b * 256 * 512 + d;
        float s2 = 0.f;
        for (int p2 = 0; p2 < 256; ++p2) s2 = fmaf(sm[p2], mb[(size_t)p2 * 512], s2);
        ctx_out[(size_t)b * 512 + d] = s2;
    }
}

// ---------------- host ----------------

extern "C" void kernel_launch(void* const* d_in, const int* in_sizes, int n_in,
                              void* d_out, int out_size, void* d_ws, size_t ws_size,
                              hipStream_t stream) {
    const float* enc    = (const float*)d_in[0];
    const float* inputs = (const float*)d_in[1];
    const void*  mlen_raw = d_in[2];
    const float* W_pre1 = (const float*)d_in[3];
    const float* W_pre2 = (const float*)d_in[4];
    const float* Wih_a  = (const float*)d_in[5];
    const float* Whh_a  = (const float*)d_in[6];
    const float* b_a    = (const float*)d_in[7];
    const float* W_q    = (const float*)d_in[8];
    const float* W_mem  = (const float*)d_in[9];
    const float* Wlc    = (const float*)d_in[10];
    const float* Wld    = (const float*)d_in[11];
    const float* v_att  = (const float*)d_in[12];
    const float* Wih_d  = (const float*)d_in[13];
    const float* Whh_d  = (const float*)d_in[14];
    const float* b_d    = (const float*)d_in[15];
    const float* W_proj = (const float*)d_in[16];
    const float* b_proj = (const float*)d_in[17];
    const float* W_gate = (const float*)d_in[18];
    const float* b_gate = (const float*)d_in[19];

    // workspace layout (floats)
    const size_t off_pre  = 0;                       // 2,097,152
    const size_t off_pm   = off_pre + 2097152;       // 1,048,576
    const size_t off_wqT  = off_pm + 1048576;        // 131,072
    const size_t off_hA0  = off_wqT + 131072;        // 32,768
    const size_t off_hA1  = off_hA0 + 32768;
    const size_t off_cA   = off_hA1 + 32768;
    const size_t off_hD0  = off_cA + 32768;
    const size_t off_hD1  = off_hD0 + 32768;
    const size_t off_cD   = off_hD1 + 32768;
    const size_t off_aw   = off_cD + 32768;          // 8,192
    const size_t off_cum  = off_aw + 8192;           // 8,192
    const size_t off_ctx0 = off_cum + 8192;          // 16,384
    const size_t off_ctx1 = off_ctx0 + 16384;        // 16,384
    const size_t off_ml   = off_ctx1 + 16384;        // 32 ints
    const size_t total_fl = off_ml + 32;
    if (ws_size < total_fl * 4) return;              // diagnostic: 0.1455 signature

    float* ws   = (float*)d_ws;
    float* pre  = ws + off_pre;
    float* pm   = ws + off_pm;
    float* wqT  = ws + off_wqT;
    float* hA[2] = { ws + off_hA0, ws + off_hA1 };
    float* cA   = ws + off_cA;
    float* hD[2] = { ws + off_hD0, ws + off_hD1 };
    float* cD   = ws + off_cD;
    float* aw   = ws + off_aw;
    float* cum  = ws + off_cum;
    float* ctxP[2] = { ws + off_ctx0, ws + off_ctx1 };
    int*   mlen = (int*)(ws + off_ml);

    float* out       = (float*)d_out;
    float* mel_out   = out;                               // 32*256*80
    float* gate_out  = out + (size_t)32 * 256 * 80;       // 32*256
    float* align_out = gate_out + (size_t)32 * 256;       // 32*256*256

    // prologue
    convert_mlen<<<1, 32, 0, stream>>>(mlen_raw, mlen);
    prenet_all<<<8192, 256, 0, stream>>>(inputs, W_pre1, W_pre2, pre);
    proc_mem<<<8192, 128, 0, stream>>>(enc, W_mem, pm);
    transpose_wq<<<512, 256, 0, stream>>>(W_q, wqT);
    {
        // zero state: hA0..ctx1 contiguous = 6*32768 + 2*8192 + 2*16384 = 245760
        zero_f<<<(245760 + 255) / 256, 256, 0, stream>>>(ws + off_hA0, 245760);
    }

    for (int t = -1; t <= 255; ++t) {
        int pc = t & 1;          // parity of t (t=-1 -> 1)
        int pn = (t + 1) & 1;    // parity of t+1
        int do_a = (t < 255), do_d = (t >= 0);
        kad<<<512, 256, 0, stream>>>(Wih_a, Whh_a, b_a, Wih_d, Whh_d, b_d,
                                     pre + (size_t)(t + 1) * 8192, ctxP[pc],
                                     hA[pc], hA[pn], cA,
                                     hD[pn], hD[pc], cD,
                                     do_a, do_d);
        kpa<<<64, 256, 0, stream>>>(enc, pm, wqT, Wlc, Wld, v_att,
                                    W_proj, b_proj, W_gate, b_gate,
                                    hA[pn],            // h_a(t+1)
                                    hD[pc],            // h_d(t)
                                    ctxP[pc],          // ctx(t)
                                    ctxP[pn],          // ctx(t+1)
                                    aw, cum, mlen,
                                    mel_out, gate_out, align_out,
                                    t, /*do_proj*/ t >= 0, /*do_attn*/ t < 255);
    }
}